// Round 4
// baseline (461.587 us; speedup 1.0000x reference)
//
#include <hip/hip_runtime.h>
#include <stdint.h>

#define N_NODES 40000
#define N_EDGES 640000
#define DD 128
#define LAYERS 3
#define SB 40  // scan blocks: 40 * 1024 >= N_NODES

typedef unsigned short u16;
typedef u16 u16x8 __attribute__((ext_vector_type(8)));
typedef short bf16x8 __attribute__((ext_vector_type(8)));
typedef float f32x4 __attribute__((ext_vector_type(4)));

__device__ inline u16 f2bf(float f) {  // RNE f32 -> bf16 (finite inputs)
  uint32_t u = __float_as_uint(f);
  return (u16)((u + 0x7fffu + ((u >> 16) & 1u)) >> 16);
}
__device__ inline float bflo2f(uint32_t u) { return __uint_as_float(u << 16); }
__device__ inline float bfhi2f(uint32_t u) { return __uint_as_float(u & 0xffff0000u); }

// ---------------- setup: convert x, convert weights, count degrees, B sentinel ----------------
// psiF: [l][o=256][k=128]; phiT: [l][n=128][k=256]; dpT: [n=128][k=128]

__global__ __launch_bounds__(256) void setup_kernel(
    const float* __restrict__ x, const float* __restrict__ psi_w,
    const float* __restrict__ phi_w, const float* __restrict__ dp_w,
    const int* __restrict__ dst, u16* __restrict__ xb, u16* __restrict__ psiF,
    u16* __restrict__ phiT, u16* __restrict__ dpT, int* __restrict__ deg,
    u16* __restrict__ Bb) {
  int b = blockIdx.x, t = threadIdx.x;
  if (b < 2500) {  // convert x: 2500*256*8 = 5.12M elements
    size_t i = ((size_t)b * 256 + t) * 8;
    float4 v0 = *(const float4*)(x + i);
    float4 v1 = *(const float4*)(x + i + 4);
    u16x8 o;
    o[0] = f2bf(v0.x); o[1] = f2bf(v0.y); o[2] = f2bf(v0.z); o[3] = f2bf(v0.w);
    o[4] = f2bf(v1.x); o[5] = f2bf(v1.y); o[6] = f2bf(v1.z); o[7] = f2bf(v1.w);
    *(u16x8*)(xb + i) = o;
  } else if (b < 3332) {  // weights: 832*256 = 212992
    int idx = (b - 2500) * 256 + t;
    if (idx < 98304) {
      int l = idx >> 15, r = idx & 32767, o = r >> 7, k = r & 127;
      int kk = k + ((o >= 128) ? 128 : 0);
      psiF[idx] = f2bf(psi_w[l * 32768 + kk * 128 + (o & 127)]);
    } else if (idx < 196608) {
      int j = idx - 98304;
      int l = j >> 15, r = j & 32767, n = r >> 8, k = r & 255;
      phiT[j] = f2bf(phi_w[l * 32768 + k * 128 + n]);
    } else {
      int j = idx - 196608;
      int n = j >> 7, k = j & 127;
      dpT[j] = f2bf(dp_w[k * 128 + n]);
    }
  } else if (b < 5832) {  // count degrees: 2500*256 = 640000
    int e = (b - 3332) * 256 + t;
    atomicAdd(&deg[dst[e]], 1);
  } else {  // sentinel row: Bb[N_NODES][*] = -inf (bf16 0xFF80)
    if (t < 64) ((uint32_t*)(Bb + (size_t)N_NODES * DD))[t] = 0xFF80FF80u;
  }
}

// ---------------- CSR build ----------------

__global__ __launch_bounds__(256) void deg_block_sum(const int* __restrict__ deg,
                                                     int* __restrict__ bsums) {
  __shared__ int red[256];
  int b = blockIdx.x, t = threadIdx.x;
  int idx = b * 1024 + t * 4;
  int s = 0;
  if (idx < N_NODES) {
    int4 v = *(const int4*)(deg + idx);
    s = v.x + v.y + v.z + v.w;
  }
  red[t] = s;
  __syncthreads();
  for (int o = 128; o > 0; o >>= 1) {
    if (t < o) red[t] += red[t + o];
    __syncthreads();
  }
  if (t == 0) bsums[b] = red[0];
}

__global__ __launch_bounds__(256) void scan_write(const int* __restrict__ deg,
                                                  const int* __restrict__ bsums,
                                                  int* __restrict__ offs,
                                                  float* __restrict__ inv_deg,
                                                  int* __restrict__ csr) {
  __shared__ int red[256];
  int b = blockIdx.x, t = threadIdx.x;
  if (b == 0 && t < 8) csr[N_EDGES + t] = N_NODES;  // sentinel pad for batched gather
  red[t] = (t < b) ? bsums[t] : 0;
  __syncthreads();
  for (int o = 128; o > 0; o >>= 1) {
    if (t < o) red[t] += red[t + o];
    __syncthreads();
  }
  int base = red[0];
  __syncthreads();
  int idx = b * 1024 + t * 4;
  int4 v = {0, 0, 0, 0};
  if (idx < N_NODES) v = *(const int4*)(deg + idx);
  int ts = v.x + v.y + v.z + v.w;
  red[t] = ts;
  __syncthreads();
  for (int o = 1; o < 256; o <<= 1) {
    int u = (t >= o) ? red[t - o] : 0;
    __syncthreads();
    red[t] += u;
    __syncthreads();
  }
  int excl = base + red[t] - ts;
  if (idx < N_NODES) {
    int4 ov;
    ov.x = excl;
    ov.y = excl + v.x;
    ov.z = ov.y + v.y;
    ov.w = ov.z + v.z;
    *(int4*)(offs + idx) = ov;
    float4 iv;
    iv.x = 1.0f / (float)(v.x > 1 ? v.x : 1);
    iv.y = 1.0f / (float)(v.y > 1 ? v.y : 1);
    iv.z = 1.0f / (float)(v.z > 1 ? v.z : 1);
    iv.w = 1.0f / (float)(v.w > 1 ? v.w : 1);
    *(float4*)(inv_deg + idx) = iv;
  }
  if (b == SB - 1 && t == 255) offs[N_NODES] = base + red[255];
}

__global__ void fill_csr_kernel(const int* __restrict__ src, const int* __restrict__ dst,
                                const int* __restrict__ offs, int* __restrict__ cnt,
                                int* __restrict__ csr) {
  int e = blockIdx.x * blockDim.x + threadIdx.x;
  if (e < N_EDGES) {
    int d = dst[e];
    int pos = offs[d] + atomicAdd(&cnt[d], 1);
    csr[pos] = src[e];
  }
}

// ---------------- fused psi GEMM: [Ab | Bb] = X[Mx128] @ Wf[128x256] ----

__global__ __launch_bounds__(256, 3) void gemm_psi(const u16* __restrict__ X0,
                                                   const u16* __restrict__ Wf,
                                                   const float* __restrict__ bias,
                                                   u16* __restrict__ Ab, u16* __restrict__ Bb) {
  __shared__ u16 Xs[64][72];
  __shared__ u16 Ws[256][72];
  const int tid = threadIdx.x;
  const int row0 = blockIdx.x * 64;
  const int w = tid >> 6, lane = tid & 63;
  const int lm = lane & 15, lq = lane >> 4;

  f32x4 acc[16];
#pragma unroll
  for (int i = 0; i < 16; ++i) acc[i] = (f32x4){0.f, 0.f, 0.f, 0.f};

#pragma unroll
  for (int c = 0; c < 2; ++c) {
#pragma unroll
    for (int i = 0; i < 2; ++i) {
      int fi = tid + i * 256;
      int r = fi >> 3, k8 = (fi & 7) * 8;
      *(u16x8*)&Xs[r][k8] = *(const u16x8*)(X0 + (size_t)(row0 + r) * DD + c * 64 + k8);
    }
#pragma unroll
    for (int i = 0; i < 8; ++i) {
      int fi = tid + i * 256;
      int n = fi >> 3, k8 = (fi & 7) * 8;
      *(u16x8*)&Ws[n][k8] = *(const u16x8*)(Wf + (size_t)n * 128 + c * 64 + k8);
    }
    __syncthreads();
#pragma unroll
    for (int ks = 0; ks < 2; ++ks) {
      bf16x8 a = *(const bf16x8*)&Xs[w * 16 + lm][lq * 8 + ks * 32];
#pragma unroll
      for (int nt = 0; nt < 16; ++nt) {
        bf16x8 b = *(const bf16x8*)&Ws[nt * 16 + lm][lq * 8 + ks * 32];
        acc[nt] = __builtin_amdgcn_mfma_f32_16x16x32_bf16(a, b, acc[nt], 0, 0, 0);
      }
    }
    __syncthreads();
  }

  float bj[8];
#pragma unroll
  for (int nt = 0; nt < 8; ++nt) bj[nt] = bias[nt * 16 + lm];
#pragma unroll
  for (int r = 0; r < 4; ++r) {
    size_t grow = (size_t)(row0 + w * 16 + lq * 4 + r) * DD;
#pragma unroll
    for (int nt = 0; nt < 8; ++nt) Ab[grow + nt * 16 + lm] = f2bf(acc[nt][r] + bj[nt]);
#pragma unroll
    for (int nt = 0; nt < 8; ++nt) Bb[grow + nt * 16 + lm] = f2bf(acc[nt + 8][r]);
  }
}

// ---------------- fused phi: gather+aggregate -> GEMM(K=256) -> (+dp GEMM if LAST) ----
// Block = 64 nodes. Wave w aggregates nodes [w*16, w*16+16) into LDS Ag, then GEMM:
// chunks 0-1 from LDS Xs (x), chunks 2-3 from LDS Ag (agg). Residual read from Xs.
// LAST: h tile written to Ag (bf16), then dp GEMM K=128 from Ag -> fp32 out.

template <bool LAST>
__global__ __launch_bounds__(256, 2) void phi_fused(
    const u16* __restrict__ X0, const u16* __restrict__ Ab, const u16* __restrict__ Bb,
    const int* __restrict__ offs, const int* __restrict__ csr,
    const float* __restrict__ inv_deg, const u16* __restrict__ Wt,
    const float* __restrict__ bias, const u16* __restrict__ dpT,
    const float* __restrict__ dp_b, u16* __restrict__ outB, float* __restrict__ outF) {
  __shared__ u16 Xs[2][64][72];
  __shared__ u16 Ws[128][72];
  __shared__ u16 Ag[2][64][72];
  const int tid = threadIdx.x;
  const int row0 = blockIdx.x * 64;
  const int w = tid >> 6, lane = tid & 63;
  const int lm = lane & 15, lq = lane >> 4;

  // stage both X chunks (k/cols 0-63 and 64-127); used for A-fragments AND residual
#pragma unroll
  for (int c = 0; c < 2; ++c)
#pragma unroll
    for (int i = 0; i < 2; ++i) {
      int fi = tid + i * 256;
      int r = fi >> 3, k8 = (fi & 7) * 8;
      *(u16x8*)&Xs[c][r][k8] = *(const u16x8*)(X0 + (size_t)(row0 + r) * DD + c * 64 + k8);
    }

  // gather + aggregate (lane = 2 channels; batches of 8 edges, sentinel-masked)
  const int c2 = lane * 2;
  const int ch = c2 >> 6, cc = c2 & 63;
  for (int j = 0; j < 16; ++j) {
    int node = row0 + w * 16 + j;
    uint32_t au = *(const uint32_t*)(Ab + (size_t)node * DD + c2);
    float ax = bflo2f(au), ay = bfhi2f(au);
    int e = offs[node], ee = offs[node + 1];
    float sx = 0.f, sy = 0.f;
    for (; e < ee; e += 8) {
      int s[8];
#pragma unroll
      for (int i = 0; i < 8; ++i) {
        int v = csr[e + i];  // csr padded with sentinels past N_EDGES
        s[i] = (e + i < ee) ? v : N_NODES;  // sentinel row = -inf -> relu contributes 0
      }
      uint32_t bv[8];
#pragma unroll
      for (int i = 0; i < 8; ++i) bv[i] = *(const uint32_t*)(Bb + (size_t)s[i] * DD + c2);
#pragma unroll
      for (int i = 0; i < 8; ++i) {
        sx += fmaxf(ax + bflo2f(bv[i]), 0.f);
        sy += fmaxf(ay + bfhi2f(bv[i]), 0.f);
      }
    }
    float wg = inv_deg[node];
    uint32_t o = (uint32_t)f2bf(sx * wg) | ((uint32_t)f2bf(sy * wg) << 16);
    *(uint32_t*)&Ag[ch][w * 16 + j][cc] = o;
  }
  __syncthreads();

  // phi GEMM: K=256 (chunks 0,1 = x from Xs; 2,3 = agg from Ag)
  f32x4 acc[8];
#pragma unroll
  for (int i = 0; i < 8; ++i) acc[i] = (f32x4){0.f, 0.f, 0.f, 0.f};
#pragma unroll
  for (int c = 0; c < 4; ++c) {
#pragma unroll
    for (int i = 0; i < 4; ++i) {
      int fi = tid + i * 256;
      int n = fi >> 3, k8 = (fi & 7) * 8;
      *(u16x8*)&Ws[n][k8] = *(const u16x8*)(Wt + (size_t)n * 256 + c * 64 + k8);
    }
    __syncthreads();
    const u16(*Asrc)[72] = (c < 2) ? Xs[c] : Ag[c - 2];
#pragma unroll
    for (int ks = 0; ks < 2; ++ks) {
      bf16x8 a = *(const bf16x8*)&Asrc[w * 16 + lm][lq * 8 + ks * 32];
#pragma unroll
      for (int nt = 0; nt < 8; ++nt) {
        bf16x8 b = *(const bf16x8*)&Ws[nt * 16 + lm][lq * 8 + ks * 32];
        acc[nt] = __builtin_amdgcn_mfma_f32_16x16x32_bf16(a, b, acc[nt], 0, 0, 0);
      }
    }
    __syncthreads();
  }

  // epilogue: v = relu(acc + bias) + x (residual from LDS Xs, bf16)
  float bj[8];
#pragma unroll
  for (int nt = 0; nt < 8; ++nt) bj[nt] = bias[nt * 16 + lm];
#pragma unroll
  for (int r = 0; r < 4; ++r) {
    int lrow = w * 16 + lq * 4 + r;
    size_t grow = (size_t)(row0 + lrow) * DD;
#pragma unroll
    for (int nt = 0; nt < 8; ++nt) {
      float res = bflo2f((uint32_t)Xs[nt >> 2][lrow][(nt & 3) * 16 + lm]);
      float v = fmaxf(acc[nt][r] + bj[nt], 0.f) + res;
      if (!LAST) {
        outB[grow + nt * 16 + lm] = f2bf(v);
      } else {
        Ag[nt >> 2][lrow][(nt & 3) * 16 + lm] = f2bf(v);  // h tile into Ag (own rows)
      }
    }
  }

  if (LAST) {
    __syncthreads();
    f32x4 acc2[8];
#pragma unroll
    for (int i = 0; i < 8; ++i) acc2[i] = (f32x4){0.f, 0.f, 0.f, 0.f};
#pragma unroll
    for (int c = 0; c < 2; ++c) {
#pragma unroll
      for (int i = 0; i < 4; ++i) {
        int fi = tid + i * 256;
        int n = fi >> 3, k8 = (fi & 7) * 8;
        *(u16x8*)&Ws[n][k8] = *(const u16x8*)(dpT + (size_t)n * DD + c * 64 + k8);
      }
      __syncthreads();
#pragma unroll
      for (int ks = 0; ks < 2; ++ks) {
        bf16x8 a = *(const bf16x8*)&Ag[c][w * 16 + lm][lq * 8 + ks * 32];
#pragma unroll
        for (int nt = 0; nt < 8; ++nt) {
          bf16x8 b = *(const bf16x8*)&Ws[nt * 16 + lm][lq * 8 + ks * 32];
          acc2[nt] = __builtin_amdgcn_mfma_f32_16x16x32_bf16(a, b, acc2[nt], 0, 0, 0);
        }
      }
      __syncthreads();
    }
    float dj[8];
#pragma unroll
    for (int nt = 0; nt < 8; ++nt) dj[nt] = dp_b[nt * 16 + lm];
#pragma unroll
    for (int r = 0; r < 4; ++r) {
      size_t grow = (size_t)(row0 + w * 16 + lq * 4 + r) * DD;
#pragma unroll
      for (int nt = 0; nt < 8; ++nt) outF[grow + nt * 16 + lm] = acc2[nt][r] + dj[nt];
    }
  }
}

// ---------------- launch ----------------

static inline char* align256(char* p) {
  return (char*)(((uintptr_t)p + 255) & ~(uintptr_t)255);
}

extern "C" void kernel_launch(void* const* d_in, const int* in_sizes, int n_in,
                              void* d_out, int out_size, void* d_ws, size_t ws_size,
                              hipStream_t stream) {
  const float* x_in  = (const float*)d_in[0];
  const int*   ei    = (const int*)d_in[1];
  const float* psi_w = (const float*)d_in[2];
  const float* psi_b = (const float*)d_in[3];
  const float* phi_w = (const float*)d_in[4];
  const float* phi_b = (const float*)d_in[5];
  const float* dp_w  = (const float*)d_in[6];
  const float* dp_b  = (const float*)d_in[7];
  float* out = (float*)d_out;

  const int* e_src = ei;
  const int* e_dst = ei + N_EDGES;

  const size_t NF = (size_t)N_NODES * DD;

  char* p = (char*)d_ws;
  int* deg = (int*)p;         p += N_NODES * sizeof(int);
  int* cnt = (int*)p;         p = align256(p + N_NODES * sizeof(int));
  int* offs = (int*)p;        p = align256(p + (N_NODES + 1) * sizeof(int));
  int* bsums = (int*)p;       p = align256(p + SB * sizeof(int));
  int* csr = (int*)p;         p = align256(p + (N_EDGES + 8) * sizeof(int));
  float* inv_deg = (float*)p; p = align256(p + N_NODES * sizeof(float));
  u16* xb0 = (u16*)p;         p = align256(p + NF * sizeof(u16));
  u16* xb1 = (u16*)p;         p = align256(p + NF * sizeof(u16));
  u16* Ab = (u16*)p;          p = align256(p + NF * sizeof(u16));
  u16* Bb = (u16*)p;          p = align256(p + (NF + DD) * sizeof(u16));  // +1 sentinel row
  u16* psiF = (u16*)p;        p = align256(p + 3 * 256 * 128 * sizeof(u16));
  u16* phiT = (u16*)p;        p = align256(p + 3 * 128 * 256 * sizeof(u16));
  u16* dpT = (u16*)p;         p = align256(p + 128 * 128 * sizeof(u16));

  hipMemsetAsync(deg, 0, 2 * N_NODES * sizeof(int), stream);  // deg + cnt contiguous

  setup_kernel<<<5833, 256, 0, stream>>>(x_in, psi_w, phi_w, dp_w, e_dst, xb0, psiF, phiT,
                                         dpT, deg, Bb);
  deg_block_sum<<<SB, 256, 0, stream>>>(deg, bsums);
  scan_write<<<SB, 256, 0, stream>>>(deg, bsums, offs, inv_deg, csr);
  fill_csr_kernel<<<(N_EDGES + 255) / 256, 256, 0, stream>>>(e_src, e_dst, offs, cnt, csr);

  const int GB = N_NODES / 64;  // 625 blocks

  u16* xbc = xb0;
  u16* xbn = xb1;
  for (int l = 0; l < LAYERS; ++l) {
    gemm_psi<<<GB, 256, 0, stream>>>(xbc, psiF + (size_t)l * 32768, psi_b + l * DD, Ab, Bb);
    if (l < LAYERS - 1) {
      phi_fused<false><<<GB, 256, 0, stream>>>(xbc, Ab, Bb, offs, csr, inv_deg,
                                               phiT + (size_t)l * 32768, phi_b + l * DD,
                                               nullptr, nullptr, xbn, nullptr);
    } else {
      phi_fused<true><<<GB, 256, 0, stream>>>(xbc, Ab, Bb, offs, csr, inv_deg,
                                              phiT + (size_t)l * 32768, phi_b + l * DD,
                                              dpT, dp_b, nullptr, out);
    }
    u16* t = xbc; xbc = xbn; xbn = t;
  }
}

// Round 5
// 290.384 us; speedup vs baseline: 1.5896x; 1.5896x over previous
//
#include <hip/hip_runtime.h>
#include <stdint.h>

#define N_NODES 40000
#define N_EDGES 640000
#define DD 128
#define LAYERS 3
#define SB 40  // scan blocks: 40 * 1024 >= N_NODES

typedef unsigned short u16;
typedef u16 u16x8 __attribute__((ext_vector_type(8)));
typedef short bf16x8 __attribute__((ext_vector_type(8)));
typedef float f32x4 __attribute__((ext_vector_type(4)));

__device__ inline u16 f2bf(float f) {  // RNE f32 -> bf16 (finite inputs)
  uint32_t u = __float_as_uint(f);
  return (u16)((u + 0x7fffu + ((u >> 16) & 1u)) >> 16);
}
__device__ inline float bflo2f(uint32_t u) { return __uint_as_float(u << 16); }
__device__ inline float bfhi2f(uint32_t u) { return __uint_as_float(u & 0xffff0000u); }

// ---------------- setup: convert x, convert weights, count degrees, B sentinel ----------------
// psiF: [l][o=256][k=128]; phiT: [l][n=128][k=256]; dpT: [n=128][k=128]

__global__ __launch_bounds__(256) void setup_kernel(
    const float* __restrict__ x, const float* __restrict__ psi_w,
    const float* __restrict__ phi_w, const float* __restrict__ dp_w,
    const int* __restrict__ dst, u16* __restrict__ xb, u16* __restrict__ psiF,
    u16* __restrict__ phiT, u16* __restrict__ dpT, int* __restrict__ deg,
    u16* __restrict__ Bb) {
  int b = blockIdx.x, t = threadIdx.x;
  if (b < 2500) {  // convert x: 2500*256*8 = 5.12M elements
    size_t i = ((size_t)b * 256 + t) * 8;
    float4 v0 = *(const float4*)(x + i);
    float4 v1 = *(const float4*)(x + i + 4);
    u16x8 o;
    o[0] = f2bf(v0.x); o[1] = f2bf(v0.y); o[2] = f2bf(v0.z); o[3] = f2bf(v0.w);
    o[4] = f2bf(v1.x); o[5] = f2bf(v1.y); o[6] = f2bf(v1.z); o[7] = f2bf(v1.w);
    *(u16x8*)(xb + i) = o;
  } else if (b < 3332) {  // weights: 832*256 = 212992
    int idx = (b - 2500) * 256 + t;
    if (idx < 98304) {
      int l = idx >> 15, r = idx & 32767, o = r >> 7, k = r & 127;
      int kk = k + ((o >= 128) ? 128 : 0);
      psiF[idx] = f2bf(psi_w[l * 32768 + kk * 128 + (o & 127)]);
    } else if (idx < 196608) {
      int j = idx - 98304;
      int l = j >> 15, r = j & 32767, n = r >> 8, k = r & 255;
      phiT[j] = f2bf(phi_w[l * 32768 + k * 128 + n]);
    } else {
      int j = idx - 196608;
      int n = j >> 7, k = j & 127;
      dpT[j] = f2bf(dp_w[k * 128 + n]);
    }
  } else if (b < 5832) {  // count degrees: 2500*256 = 640000
    int e = (b - 3332) * 256 + t;
    atomicAdd(&deg[dst[e]], 1);
  } else {  // sentinel row: Bb[N_NODES][*] = -inf (bf16 0xFF80)
    if (t < 64) ((uint32_t*)(Bb + (size_t)N_NODES * DD))[t] = 0xFF80FF80u;
  }
}

// ---------------- CSR build ----------------

__global__ __launch_bounds__(256) void deg_block_sum(const int* __restrict__ deg,
                                                     int* __restrict__ bsums) {
  __shared__ int red[256];
  int b = blockIdx.x, t = threadIdx.x;
  int idx = b * 1024 + t * 4;
  int s = 0;
  if (idx < N_NODES) {
    int4 v = *(const int4*)(deg + idx);
    s = v.x + v.y + v.z + v.w;
  }
  red[t] = s;
  __syncthreads();
  for (int o = 128; o > 0; o >>= 1) {
    if (t < o) red[t] += red[t + o];
    __syncthreads();
  }
  if (t == 0) bsums[b] = red[0];
}

__global__ __launch_bounds__(256) void scan_write(const int* __restrict__ deg,
                                                  const int* __restrict__ bsums,
                                                  int* __restrict__ offs,
                                                  float* __restrict__ inv_deg,
                                                  int* __restrict__ csr) {
  __shared__ int red[256];
  int b = blockIdx.x, t = threadIdx.x;
  if (b == 0 && t < 8) csr[N_EDGES + t] = N_NODES;  // sentinel pad for batched gather
  red[t] = (t < b) ? bsums[t] : 0;
  __syncthreads();
  for (int o = 128; o > 0; o >>= 1) {
    if (t < o) red[t] += red[t + o];
    __syncthreads();
  }
  int base = red[0];
  __syncthreads();
  int idx = b * 1024 + t * 4;
  int4 v = {0, 0, 0, 0};
  if (idx < N_NODES) v = *(const int4*)(deg + idx);
  int ts = v.x + v.y + v.z + v.w;
  red[t] = ts;
  __syncthreads();
  for (int o = 1; o < 256; o <<= 1) {
    int u = (t >= o) ? red[t - o] : 0;
    __syncthreads();
    red[t] += u;
    __syncthreads();
  }
  int excl = base + red[t] - ts;
  if (idx < N_NODES) {
    int4 ov;
    ov.x = excl;
    ov.y = excl + v.x;
    ov.z = ov.y + v.y;
    ov.w = ov.z + v.z;
    *(int4*)(offs + idx) = ov;
    float4 iv;
    iv.x = 1.0f / (float)(v.x > 1 ? v.x : 1);
    iv.y = 1.0f / (float)(v.y > 1 ? v.y : 1);
    iv.z = 1.0f / (float)(v.z > 1 ? v.z : 1);
    iv.w = 1.0f / (float)(v.w > 1 ? v.w : 1);
    *(float4*)(inv_deg + idx) = iv;
  }
  if (b == SB - 1 && t == 255) offs[N_NODES] = base + red[255];
}

__global__ void fill_csr_kernel(const int* __restrict__ src, const int* __restrict__ dst,
                                const int* __restrict__ offs, int* __restrict__ cnt,
                                int* __restrict__ csr) {
  int e = blockIdx.x * blockDim.x + threadIdx.x;
  if (e < N_EDGES) {
    int d = dst[e];
    int pos = offs[d] + atomicAdd(&cnt[d], 1);
    csr[pos] = src[e];
  }
}

// ---------------- fused psi GEMM: [Ab | Bb] = X[Mx128] @ Wf[128x256] ----

__global__ __launch_bounds__(256, 3) void gemm_psi(const u16* __restrict__ X0,
                                                   const u16* __restrict__ Wf,
                                                   const float* __restrict__ bias,
                                                   u16* __restrict__ Ab, u16* __restrict__ Bb) {
  __shared__ u16 Xs[64][72];
  __shared__ u16 Ws[256][72];
  const int tid = threadIdx.x;
  const int row0 = blockIdx.x * 64;
  const int w = tid >> 6, lane = tid & 63;
  const int lm = lane & 15, lq = lane >> 4;

  f32x4 acc[16];
#pragma unroll
  for (int i = 0; i < 16; ++i) acc[i] = (f32x4){0.f, 0.f, 0.f, 0.f};

#pragma unroll
  for (int c = 0; c < 2; ++c) {
#pragma unroll
    for (int i = 0; i < 2; ++i) {
      int fi = tid + i * 256;
      int r = fi >> 3, k8 = (fi & 7) * 8;
      *(u16x8*)&Xs[r][k8] = *(const u16x8*)(X0 + (size_t)(row0 + r) * DD + c * 64 + k8);
    }
#pragma unroll
    for (int i = 0; i < 8; ++i) {
      int fi = tid + i * 256;
      int n = fi >> 3, k8 = (fi & 7) * 8;
      *(u16x8*)&Ws[n][k8] = *(const u16x8*)(Wf + (size_t)n * 128 + c * 64 + k8);
    }
    __syncthreads();
#pragma unroll
    for (int ks = 0; ks < 2; ++ks) {
      bf16x8 a = *(const bf16x8*)&Xs[w * 16 + lm][lq * 8 + ks * 32];
#pragma unroll
      for (int nt = 0; nt < 16; ++nt) {
        bf16x8 b = *(const bf16x8*)&Ws[nt * 16 + lm][lq * 8 + ks * 32];
        acc[nt] = __builtin_amdgcn_mfma_f32_16x16x32_bf16(a, b, acc[nt], 0, 0, 0);
      }
    }
    __syncthreads();
  }

  float bj[8];
#pragma unroll
  for (int nt = 0; nt < 8; ++nt) bj[nt] = bias[nt * 16 + lm];
#pragma unroll
  for (int r = 0; r < 4; ++r) {
    size_t grow = (size_t)(row0 + w * 16 + lq * 4 + r) * DD;
#pragma unroll
    for (int nt = 0; nt < 8; ++nt) Ab[grow + nt * 16 + lm] = f2bf(acc[nt][r] + bj[nt]);
#pragma unroll
    for (int nt = 0; nt < 8; ++nt) Bb[grow + nt * 16 + lm] = f2bf(acc[nt + 8][r]);
  }
}

// ---------------- aggregation: agg[i] = inv_deg[i] * sum_e relu(A[i] + B[src_e]) ----
// one wave per node, lane = 2 channels, batch-8 sentinel gather (no remainder loop)

__global__ __launch_bounds__(256) void aggregate_bf16(
    const u16* __restrict__ A, const u16* __restrict__ B, const int* __restrict__ offs,
    const int* __restrict__ csr, const float* __restrict__ inv_deg, u16* __restrict__ agg) {
  int node = blockIdx.x * 4 + (threadIdx.x >> 6);
  int lane = threadIdx.x & 63;
  const int c2 = lane * 2;
  uint32_t au = *(const uint32_t*)(A + (size_t)node * DD + c2);
  float ax = bflo2f(au), ay = bfhi2f(au);
  int e = offs[node], ee = offs[node + 1];
  float sx = 0.f, sy = 0.f;
  for (; e < ee; e += 8) {
    int s[8];
#pragma unroll
    for (int i = 0; i < 8; ++i) {
      int v = csr[e + i];  // csr padded with sentinels past N_EDGES
      s[i] = (e + i < ee) ? v : N_NODES;  // sentinel row = -inf -> relu contributes 0
    }
    uint32_t bv[8];
#pragma unroll
    for (int i = 0; i < 8; ++i) bv[i] = *(const uint32_t*)(B + (size_t)s[i] * DD + c2);
#pragma unroll
    for (int i = 0; i < 8; ++i) {
      sx += fmaxf(ax + bflo2f(bv[i]), 0.f);
      sy += fmaxf(ay + bfhi2f(bv[i]), 0.f);
    }
  }
  float wg = inv_deg[node];
  uint32_t o = (uint32_t)f2bf(sx * wg) | ((uint32_t)f2bf(sy * wg) << 16);
  *(uint32_t*)(agg + (size_t)node * DD + c2) = o;
}

// ---------------- phi GEMM (K=256: x | agg), residual from global bf16 x ----
// LAST: h tile -> LDS -> dp GEMM (K=128) -> fp32 out

template <bool LAST>
__global__ __launch_bounds__(256, 3) void gemm_phi(
    const u16* __restrict__ X0, const u16* __restrict__ X1, const u16* __restrict__ Wt,
    const float* __restrict__ bias, const u16* __restrict__ dpT,
    const float* __restrict__ dp_b, u16* __restrict__ outB, float* __restrict__ outF) {
  __shared__ u16 Xs[2][64][72];
  __shared__ u16 Ws[128][72];
  const int tid = threadIdx.x;
  const int row0 = blockIdx.x * 64;
  const int w = tid >> 6, lane = tid & 63;
  const int lm = lane & 15, lq = lane >> 4;

  f32x4 acc[8];
#pragma unroll
  for (int i = 0; i < 8; ++i) acc[i] = (f32x4){0.f, 0.f, 0.f, 0.f};

#pragma unroll
  for (int c = 0; c < 4; ++c) {
    const u16* Xsrc = (c < 2) ? (X0 + c * 64) : (X1 + (c - 2) * 64);
#pragma unroll
    for (int i = 0; i < 2; ++i) {
      int fi = tid + i * 256;
      int r = fi >> 3, k8 = (fi & 7) * 8;
      *(u16x8*)&Xs[c & 1][r][k8] = *(const u16x8*)(Xsrc + (size_t)(row0 + r) * DD + k8);
    }
#pragma unroll
    for (int i = 0; i < 4; ++i) {
      int fi = tid + i * 256;
      int n = fi >> 3, k8 = (fi & 7) * 8;
      *(u16x8*)&Ws[n][k8] = *(const u16x8*)(Wt + (size_t)n * 256 + c * 64 + k8);
    }
    __syncthreads();
#pragma unroll
    for (int ks = 0; ks < 2; ++ks) {
      bf16x8 a = *(const bf16x8*)&Xs[c & 1][w * 16 + lm][lq * 8 + ks * 32];
#pragma unroll
      for (int nt = 0; nt < 8; ++nt) {
        bf16x8 b = *(const bf16x8*)&Ws[nt * 16 + lm][lq * 8 + ks * 32];
        acc[nt] = __builtin_amdgcn_mfma_f32_16x16x32_bf16(a, b, acc[nt], 0, 0, 0);
      }
    }
    __syncthreads();
  }

  // epilogue: v = relu(acc + bias) + x  (residual from global bf16 x, L2-hot)
  float bj[8];
#pragma unroll
  for (int nt = 0; nt < 8; ++nt) bj[nt] = bias[nt * 16 + lm];
#pragma unroll
  for (int r = 0; r < 4; ++r) {
    int lrow = w * 16 + lq * 4 + r;
    size_t grow = (size_t)(row0 + lrow) * DD;
#pragma unroll
    for (int nt = 0; nt < 8; ++nt) {
      float res = bflo2f((uint32_t)X0[grow + nt * 16 + lm]);
      float v = fmaxf(acc[nt][r] + bj[nt], 0.f) + res;
      if (!LAST) {
        outB[grow + nt * 16 + lm] = f2bf(v);
      } else {
        Xs[nt >> 2][lrow][(nt & 3) * 16 + lm] = f2bf(v);  // h tile into Xs
      }
    }
  }

  if (LAST) {
    __syncthreads();
    f32x4 acc2[8];
#pragma unroll
    for (int i = 0; i < 8; ++i) acc2[i] = (f32x4){0.f, 0.f, 0.f, 0.f};
#pragma unroll
    for (int c = 0; c < 2; ++c) {
#pragma unroll
      for (int i = 0; i < 4; ++i) {
        int fi = tid + i * 256;
        int n = fi >> 3, k8 = (fi & 7) * 8;
        *(u16x8*)&Ws[n][k8] = *(const u16x8*)(dpT + (size_t)n * DD + c * 64 + k8);
      }
      __syncthreads();
#pragma unroll
      for (int ks = 0; ks < 2; ++ks) {
        bf16x8 a = *(const bf16x8*)&Xs[c][w * 16 + lm][lq * 8 + ks * 32];
#pragma unroll
        for (int nt = 0; nt < 8; ++nt) {
          bf16x8 b = *(const bf16x8*)&Ws[nt * 16 + lm][lq * 8 + ks * 32];
          acc2[nt] = __builtin_amdgcn_mfma_f32_16x16x32_bf16(a, b, acc2[nt], 0, 0, 0);
        }
      }
      __syncthreads();
    }
    float dj[8];
#pragma unroll
    for (int nt = 0; nt < 8; ++nt) dj[nt] = dp_b[nt * 16 + lm];
#pragma unroll
    for (int r = 0; r < 4; ++r) {
      size_t grow = (size_t)(row0 + w * 16 + lq * 4 + r) * DD;
#pragma unroll
      for (int nt = 0; nt < 8; ++nt) outF[grow + nt * 16 + lm] = acc2[nt][r] + dj[nt];
    }
  }
}

// ---------------- launch ----------------

static inline char* align256(char* p) {
  return (char*)(((uintptr_t)p + 255) & ~(uintptr_t)255);
}

extern "C" void kernel_launch(void* const* d_in, const int* in_sizes, int n_in,
                              void* d_out, int out_size, void* d_ws, size_t ws_size,
                              hipStream_t stream) {
  const float* x_in  = (const float*)d_in[0];
  const int*   ei    = (const int*)d_in[1];
  const float* psi_w = (const float*)d_in[2];
  const float* psi_b = (const float*)d_in[3];
  const float* phi_w = (const float*)d_in[4];
  const float* phi_b = (const float*)d_in[5];
  const float* dp_w  = (const float*)d_in[6];
  const float* dp_b  = (const float*)d_in[7];
  float* out = (float*)d_out;

  const int* e_src = ei;
  const int* e_dst = ei + N_EDGES;

  const size_t NF = (size_t)N_NODES * DD;

  char* p = (char*)d_ws;
  int* deg = (int*)p;         p += N_NODES * sizeof(int);   // N_NODES*4 is 256-aligned
  int* cnt = (int*)p;         p = align256(p + N_NODES * sizeof(int));
  int* offs = (int*)p;        p = align256(p + (N_NODES + 1) * sizeof(int));
  int* bsums = (int*)p;       p = align256(p + SB * sizeof(int));
  int* csr = (int*)p;         p = align256(p + (N_EDGES + 8) * sizeof(int));
  float* inv_deg = (float*)p; p = align256(p + N_NODES * sizeof(float));
  u16* xb0 = (u16*)p;         p = align256(p + NF * sizeof(u16));
  u16* xb1 = (u16*)p;         p = align256(p + NF * sizeof(u16));
  u16* Ab = (u16*)p;          p = align256(p + NF * sizeof(u16));
  u16* Bb = (u16*)p;          p = align256(p + (NF + DD) * sizeof(u16));  // +1 sentinel row
  u16* aggb = (u16*)p;        p = align256(p + NF * sizeof(u16));
  u16* psiF = (u16*)p;        p = align256(p + 3 * 256 * 128 * sizeof(u16));
  u16* phiT = (u16*)p;        p = align256(p + 3 * 128 * 256 * sizeof(u16));
  u16* dpT = (u16*)p;         p = align256(p + 128 * 128 * sizeof(u16));

  hipMemsetAsync(deg, 0, 2 * N_NODES * sizeof(int), stream);  // deg + cnt contiguous

  setup_kernel<<<5833, 256, 0, stream>>>(x_in, psi_w, phi_w, dp_w, e_dst, xb0, psiF, phiT,
                                         dpT, deg, Bb);
  deg_block_sum<<<SB, 256, 0, stream>>>(deg, bsums);
  scan_write<<<SB, 256, 0, stream>>>(deg, bsums, offs, inv_deg, csr);
  fill_csr_kernel<<<(N_EDGES + 255) / 256, 256, 0, stream>>>(e_src, e_dst, offs, cnt, csr);

  const int GB = N_NODES / 64;  // 625 blocks

  u16* xbc = xb0;
  u16* xbn = xb1;
  for (int l = 0; l < LAYERS; ++l) {
    gemm_psi<<<GB, 256, 0, stream>>>(xbc, psiF + (size_t)l * 32768, psi_b + l * DD, Ab, Bb);
    aggregate_bf16<<<N_NODES / 4, 256, 0, stream>>>(Ab, Bb, offs, csr, inv_deg, aggb);
    if (l < LAYERS - 1) {
      gemm_phi<false><<<GB, 256, 0, stream>>>(xbc, aggb, phiT + (size_t)l * 32768,
                                              phi_b + l * DD, nullptr, nullptr, xbn, nullptr);
    } else {
      gemm_phi<true><<<GB, 256, 0, stream>>>(xbc, aggb, phiT + (size_t)l * 32768,
                                             phi_b + l * DD, dpT, dp_b, nullptr, out);
    }
    u16* t = xbc; xbc = xbn; xbn = t;
  }
}